// Round 3
// baseline (8300.053 us; speedup 1.0000x reference)
//
#include <hip/hip_runtime.h>
#include <hip/hip_bf16.h>
#include <math.h>

#define B_SZ   256
#define D_DIM  256
#define C_DIM  64
#define N_CAND 200000
#define K_TOP  5
#define SLAB   1024
#define SUBT   4
#define BC     256
#define BQ     64
#define KD     32
#define NSLABS ((N_CAND + SLAB - 1) / SLAB)   // 196

__device__ __forceinline__ bool better(float v1, int i1, float v2, int i2) {
    return (v1 > v2) || (v1 == v2 && i1 < i2);
}

// insert (v,idx) into a sorted-desc 6-list held in registers (constant-indexed)
__device__ __forceinline__ void insert6(float* lv, int* li, float v, int idx) {
    if (better(v, idx, lv[5], li[5])) {
        lv[5] = v; li[5] = idx;
        #pragma unroll
        for (int k = 5; k > 0; --k) {
            if (better(lv[k], li[k], lv[k - 1], li[k - 1])) {
                float tv = lv[k]; lv[k] = lv[k - 1]; lv[k - 1] = tv;
                int   ti = li[k]; li[k] = li[k - 1]; li[k - 1] = ti;
            }
        }
    }
}

// merge two sorted-desc 6-lists (LDS pointers) -> top-6 into register arrays
__device__ __forceinline__ void merge6(const float* av, const int* ai,
                                       const float* bv, const int* bi,
                                       float* ov, int* oi) {
    int ia = 0, ib = 0;
    #pragma unroll
    for (int k = 0; k < 6; ++k) {
        bool ta;
        if (ia >= 6)      ta = false;
        else if (ib >= 6) ta = true;
        else              ta = better(av[ia], ai[ia], bv[ib], bi[ib]);
        if (ta) { ov[k] = av[ia]; oi[k] = ai[ia]; ++ia; }
        else    { ov[k] = bv[ib]; oi[k] = bi[ib]; ++ib; }
    }
}

__global__ void k_init(int* pos_of, float* accp) {
    int i = blockIdx.x * 256 + threadIdx.x;
    if (i < N_CAND) pos_of[i] = -1;
    if (i == 0) accp[0] = 0.f;
}

__global__ void k_scatter(const int* __restrict__ trg, int* __restrict__ pos_of) {
    int j = threadIdx.x;   // 256 threads; atomicMax => last batch row wins on duplicates
    atomicMax(&pos_of[trg[j]], j);
}

// per-row: f_norm, logits = f @ W + b, softmax
__global__ __launch_bounds__(256) void k_prep(const float* __restrict__ features,
                                              const float* __restrict__ W,
                                              const float* __restrict__ bias,
                                              float* __restrict__ f_norm,
                                              float* __restrict__ softm) {
    int b = blockIdx.x, t = threadIdx.x;
    __shared__ float row[256];
    __shared__ float red[256];
    float x = features[b * D_DIM + t];
    row[t] = x; red[t] = x * x;
    __syncthreads();
    for (int s = 128; s > 0; s >>= 1) {
        if (t < s) red[t] += red[t + s];
        __syncthreads();
    }
    float nrm = fmaxf(sqrtf(red[0]), 1e-12f);
    f_norm[b * D_DIM + t] = x / nrm;
    if (t < C_DIM) {
        float acc = bias[t];
        for (int d = 0; d < D_DIM; ++d) acc = fmaf(row[d], W[d * C_DIM + t], acc);
        float mx = acc;
        for (int off = 32; off > 0; off >>= 1) mx = fmaxf(mx, __shfl_xor(mx, off, 64));
        float e = expf(acc - mx);
        float ssum = e;
        for (int off = 32; off > 0; off >>= 1) ssum += __shfl_xor(ssum, off, 64);
        softm[b * C_DIM + t] = e / ssum;
    }
}

// fused GEMM (M x 200000, K=256) + per-(query,slab) top-6 partials.
// grid = (NSLABS, M/64), block = 256. Thread (qg=t>>5,l5=t&31) computes
// 8 queries x 8 strided candidates.
__global__ __launch_bounds__(256) void dist_topk(const float* __restrict__ Qm,
                                                 const float* __restrict__ fea_bank,
                                                 const float* __restrict__ f_norm,
                                                 const int* __restrict__ pos_of,
                                                 float* __restrict__ pval,
                                                 int* __restrict__ pidx) {
    __shared__ float qs[BQ][KD + 1];
    __shared__ float cs[BC][KD + 1];
    __shared__ float mv[8][32][6];
    __shared__ int   mi[8][32][6];
    __shared__ float gval[BQ][6];
    __shared__ int   gidx[BQ][6];

    const int slab = blockIdx.x;
    const int qt   = blockIdx.y;
    const int t  = threadIdx.x;
    const int qg = t >> 5;
    const int l5 = t & 31;

    if (t < BQ) {
        #pragma unroll
        for (int k = 0; k < 6; ++k) { gval[t][k] = -3.4e38f; gidx[t][k] = 0x7fffffff; }
    }
    __syncthreads();

    const int lr = t >> 3;        // load row group 0..31
    const int ld = (t & 7) * 4;   // load dim offset

    for (int sub = 0; sub < SUBT; ++sub) {
        const int cbase = slab * SLAB + sub * BC;

        float acc[8][8];
        #pragma unroll
        for (int i = 0; i < 8; ++i)
            #pragma unroll
            for (int j = 0; j < 8; ++j) acc[i][j] = 0.f;

        for (int k0 = 0; k0 < D_DIM; k0 += KD) {
            #pragma unroll
            for (int i = 0; i < 2; ++i) {
                int rr = lr + 32 * i;
                const float* src = Qm + (size_t)(qt * BQ + rr) * D_DIM + k0 + ld;
                float4 v = *(const float4*)src;
                qs[rr][ld + 0] = v.x; qs[rr][ld + 1] = v.y;
                qs[rr][ld + 2] = v.z; qs[rr][ld + 3] = v.w;
            }
            #pragma unroll
            for (int i = 0; i < 8; ++i) {
                int r = lr + 32 * i;
                int n = cbase + r;
                int nc = n < N_CAND ? n : N_CAND - 1;
                int p = pos_of[nc];
                const float* src = (p >= 0) ? (f_norm + (size_t)p * D_DIM)
                                            : (fea_bank + (size_t)nc * D_DIM);
                float4 v = *(const float4*)(src + k0 + ld);
                cs[r][ld + 0] = v.x; cs[r][ld + 1] = v.y;
                cs[r][ld + 2] = v.z; cs[r][ld + 3] = v.w;
            }
            __syncthreads();
            #pragma unroll
            for (int d = 0; d < KD; ++d) {
                float qv[8], cv[8];
                #pragma unroll
                for (int i = 0; i < 8; ++i) qv[i] = qs[qg * 8 + i][d];
                #pragma unroll
                for (int j = 0; j < 8; ++j) cv[j] = cs[l5 + 32 * j][d];
                #pragma unroll
                for (int i = 0; i < 8; ++i)
                    #pragma unroll
                    for (int j = 0; j < 8; ++j)
                        acc[i][j] = fmaf(qv[i], cv[j], acc[i][j]);
            }
            __syncthreads();
        }

        // ---- top-k update (qi must be unrolled: acc is a register array) ----
        #pragma unroll
        for (int qi = 0; qi < 8; ++qi) {
            float lv[6]; int li[6];
            #pragma unroll
            for (int k = 0; k < 6; ++k) { lv[k] = -3.4e38f; li[k] = 0x7fffffff; }
            #pragma unroll
            for (int j = 0; j < 8; ++j) {
                int n = cbase + l5 + 32 * j;
                if (n < N_CAND) insert6(lv, li, acc[qi][j], n);
            }
            #pragma unroll
            for (int k = 0; k < 6; ++k) { mv[qg][l5][k] = lv[k]; mi[qg][l5][k] = li[k]; }
            __syncthreads();
            #pragma unroll
            for (int w = 16; w >= 1; w >>= 1) {
                if (l5 < w) {
                    float ov[6]; int oi[6];
                    merge6(mv[qg][l5], mi[qg][l5], mv[qg][l5 + w], mi[qg][l5 + w], ov, oi);
                    #pragma unroll
                    for (int k = 0; k < 6; ++k) { mv[qg][l5][k] = ov[k]; mi[qg][l5][k] = oi[k]; }
                }
                __syncthreads();
            }
            if (l5 == 0) {
                float ov[6]; int oi[6];
                merge6(gval[qg * 8 + qi], gidx[qg * 8 + qi], mv[qg][0], mi[qg][0], ov, oi);
                #pragma unroll
                for (int k = 0; k < 6; ++k) { gval[qg * 8 + qi][k] = ov[k]; gidx[qg * 8 + qi][k] = oi[k]; }
            }
            __syncthreads();
        }
    }

    if (t < BQ) {
        int q = qt * BQ + t;
        size_t base = ((size_t)q * NSLABS + slab) * 6;
        #pragma unroll
        for (int k = 0; k < 6; ++k) { pval[base + k] = gval[t][k]; pidx[base + k] = gidx[t][k]; }
    }
}

// grid = M blocks; merge NSLABS*6 partials -> top-6, write indices 1..5
__global__ __launch_bounds__(256) void topk_merge(const float* __restrict__ pval,
                                                  const int* __restrict__ pidx,
                                                  int* __restrict__ out_idx) {
    int q = blockIdx.x, t = threadIdx.x;
    const int total = NSLABS * 6;
    float lv[6]; int li[6];
    #pragma unroll
    for (int k = 0; k < 6; ++k) { lv[k] = -3.4e38f; li[k] = 0x7fffffff; }
    size_t base = (size_t)q * total;
    for (int e = t; e < total; e += 256) insert6(lv, li, pval[base + e], pidx[base + e]);
    __shared__ float sv[256][6];
    __shared__ int   si[256][6];
    #pragma unroll
    for (int k = 0; k < 6; ++k) { sv[t][k] = lv[k]; si[t][k] = li[k]; }
    __syncthreads();
    for (int w = 128; w >= 1; w >>= 1) {
        if (t < w) {
            float ov[6]; int oi[6];
            merge6(sv[t], si[t], sv[t + w], si[t + w], ov, oi);
            #pragma unroll
            for (int k = 0; k < 6; ++k) { sv[t][k] = ov[k]; si[t][k] = oi[k]; }
        }
        __syncthreads();
    }
    if (t == 0) {
        for (int k = 1; k < 6; ++k) out_idx[q * K_TOP + k - 1] = si[0][k];
    }
}

// gather 1280 neighbor rows (with bank substitution) into Q2
__global__ void k_gather(const int* __restrict__ idx, const float* __restrict__ fea_bank,
                         const float* __restrict__ f_norm, const int* __restrict__ pos_of,
                         float* __restrict__ Q2) {
    int r = blockIdx.x, t = threadIdx.x;   // 64 threads
    int n = idx[r];
    int p = pos_of[n];
    const float* src = (p >= 0) ? (f_norm + (size_t)p * D_DIM)
                                : (fea_bank + (size_t)n * D_DIM);
    float4 v = ((const float4*)src)[t];
    ((float4*)(Q2 + (size_t)r * D_DIM))[t] = v;
}

// per-b KL terms; one wave per block
__global__ void k_loss(const float* __restrict__ softm, const float* __restrict__ score_bank,
                       const int* __restrict__ pos_of, const int* __restrict__ idx_near,
                       const int* __restrict__ idx_nn, const int* __restrict__ trg,
                       float* accp) {
    int b = blockIdx.x, c = threadIdx.x;   // 64 threads
    float p_bc = softm[b * C_DIM + c];
    float part = 0.f;
    for (int k = 0; k < K_TOP; ++k) {
        for (int j = 0; j < K_TOP; ++j) {
            int n = idx_nn[(b * K_TOP + k) * K_TOP + j];
            int p = pos_of[n];
            const float* srow = (p >= 0) ? (softm + (size_t)p * C_DIM)
                                         : (score_bank + (size_t)n * C_DIM);
            float s = srow[c];
            float v = s * (logf(s) - p_bc);
            for (int off = 32; off > 0; off >>= 1) v += __shfl_down(v, off, 64);
            if (c == 0) part += 0.1f * v;
        }
    }
    for (int k = 0; k < K_TOP; ++k) {
        int n = idx_near[b * K_TOP + k];
        int p = pos_of[n];
        const float* srow = (p >= 0) ? (softm + (size_t)p * C_DIM)
                                     : (score_bank + (size_t)n * C_DIM);
        float s = srow[c];
        float v = s * (logf(s) - p_bc);
        for (int off = 32; off > 0; off >>= 1) v += __shfl_down(v, off, 64);
        if (c == 0) {
            int m = 0;
            for (int j = 0; j < K_TOP; ++j)
                m += (idx_nn[(b * K_TOP + k) * K_TOP + j] == trg[b]) ? 1 : 0;
            float w = (m > 0) ? (float)m : 0.1f;
            part += w * v;
        }
    }
    if (c == 0) atomicAdd(accp, part * (1.0f / (float)B_SZ));
}

// gentropy + final write
__global__ void k_final(const float* __restrict__ softm, const float* __restrict__ accp,
                        float* __restrict__ out) {
    int c = threadIdx.x;   // 64
    float m = 0.f;
    for (int b = 0; b < B_SZ; ++b) m += softm[b * C_DIM + c];
    m *= (1.0f / (float)B_SZ);
    float g = m * logf(m + 1e-5f);
    for (int off = 32; off > 0; off >>= 1) g += __shfl_down(g, off, 64);
    if (c == 0) out[0] = accp[0] + g;
}

extern "C" void kernel_launch(void* const* d_in, const int* in_sizes, int n_in,
                              void* d_out, int out_size, void* d_ws, size_t ws_size,
                              hipStream_t stream) {
    const float* features   = (const float*)d_in[0];
    const float* W          = (const float*)d_in[1];
    const float* bias       = (const float*)d_in[2];
    const float* fea_bank   = (const float*)d_in[3];
    const float* score_bank = (const float*)d_in[4];
    const int*   trg        = (const int*)d_in[5];
    float* out = (float*)d_out;

    char* ws = (char*)d_ws;
    size_t off = 0;
    auto alloc = [&](size_t bytes) -> void* {
        void* p = ws + off;
        off = (off + bytes + 255) & ~(size_t)255;
        return p;
    };
    float* f_norm   = (float*)alloc((size_t)B_SZ * D_DIM * 4);
    float* softm    = (float*)alloc((size_t)B_SZ * C_DIM * 4);
    int*   pos_of   = (int*)alloc((size_t)N_CAND * 4);
    float* accp     = (float*)alloc(4);
    int*   idx_near = (int*)alloc((size_t)B_SZ * K_TOP * 4);
    int*   idx_nn   = (int*)alloc((size_t)B_SZ * K_TOP * K_TOP * 4);
    float* Q2       = (float*)alloc((size_t)B_SZ * K_TOP * D_DIM * 4);
    float* pv1      = (float*)alloc((size_t)B_SZ * NSLABS * 6 * 4);
    int*   pi1      = (int*)alloc((size_t)B_SZ * NSLABS * 6 * 4);
    float* pv2      = (float*)alloc((size_t)B_SZ * K_TOP * NSLABS * 6 * 4);
    int*   pi2      = (int*)alloc((size_t)B_SZ * K_TOP * NSLABS * 6 * 4);

    k_init<<<dim3((N_CAND + 255) / 256), dim3(256), 0, stream>>>(pos_of, accp);
    k_scatter<<<dim3(1), dim3(256), 0, stream>>>(trg, pos_of);
    k_prep<<<dim3(B_SZ), dim3(256), 0, stream>>>(features, W, bias, f_norm, softm);

    dist_topk<<<dim3(NSLABS, B_SZ / BQ), dim3(256), 0, stream>>>(
        f_norm, fea_bank, f_norm, pos_of, pv1, pi1);
    topk_merge<<<dim3(B_SZ), dim3(256), 0, stream>>>(pv1, pi1, idx_near);

    k_gather<<<dim3(B_SZ * K_TOP), dim3(64), 0, stream>>>(idx_near, fea_bank, f_norm, pos_of, Q2);

    dist_topk<<<dim3(NSLABS, (B_SZ * K_TOP) / BQ), dim3(256), 0, stream>>>(
        Q2, fea_bank, f_norm, pos_of, pv2, pi2);
    topk_merge<<<dim3(B_SZ * K_TOP), dim3(256), 0, stream>>>(pv2, pi2, idx_nn);

    k_loss<<<dim3(B_SZ), dim3(64), 0, stream>>>(softm, score_bank, pos_of, idx_near, idx_nn, trg, accp);
    k_final<<<dim3(1), dim3(64), 0, stream>>>(softm, accp, out);
}

// Round 4
// 2005.575 us; speedup vs baseline: 4.1385x; 4.1385x over previous
//
#include <hip/hip_runtime.h>
#include <hip/hip_bf16.h>
#include <math.h>

#define B_SZ   256
#define D_DIM  256
#define C_DIM  64
#define N_CAND 200000
#define K_TOP  5
#define SLAB   1024
#define CHUNK  64
#define NCHUNK (SLAB / CHUNK)                 // 16
#define NSLABS ((N_CAND + SLAB - 1) / SLAB)   // 196

typedef short bf16x8 __attribute__((ext_vector_type(8)));   // 8 bf16 in 4 VGPRs
typedef float f32x16 __attribute__((ext_vector_type(16)));

__device__ __forceinline__ bool better(float v1, int i1, float v2, int i2) {
    return (v1 > v2) || (v1 == v2 && i1 < i2);
}

__device__ __forceinline__ void insert6(float* lv, int* li, float v, int idx) {
    if (better(v, idx, lv[5], li[5])) {
        lv[5] = v; li[5] = idx;
        #pragma unroll
        for (int k = 5; k > 0; --k) {
            if (better(lv[k], li[k], lv[k - 1], li[k - 1])) {
                float tv = lv[k]; lv[k] = lv[k - 1]; lv[k - 1] = tv;
                int   ti = li[k]; li[k] = li[k - 1]; li[k - 1] = ti;
            }
        }
    }
}

__device__ __forceinline__ void merge6(const float* av, const int* ai,
                                       const float* bv, const int* bi,
                                       float* ov, int* oi) {
    int ia = 0, ib = 0;
    #pragma unroll
    for (int k = 0; k < 6; ++k) {
        bool ta;
        if (ia >= 6)      ta = false;
        else if (ib >= 6) ta = true;
        else              ta = better(av[ia], ai[ia], bv[ib], bi[ib]);
        if (ta) { ov[k] = av[ia]; oi[k] = ai[ia]; ++ia; }
        else    { ov[k] = bv[ib]; oi[k] = bi[ib]; ++ib; }
    }
}

__device__ __forceinline__ unsigned short bf16rne(float x) {
    unsigned int u = __float_as_uint(x);
    unsigned int r = u + 0x7fffu + ((u >> 16) & 1u);
    return (unsigned short)(r >> 16);
}

// LDS chunk layout: 16B chunk (8 bf16) for (row r, k-group) at index
//   idx = (kstep*2 + (r>>5))*2*32 + ((k>>3)&1)*32 + (r&31),  kstep = k>>4
// A wave's 64 fragment reads at fixed (kstep, rowgrp) are lanes l -> idx base+l
// => one contiguous 1KB region => bank-optimal.
__device__ __forceinline__ void stage16(short* dst, int r, int kk, float4 v) {
    int idx = ((kk >> 4) * 128) + ((r >> 5) * 64) + (((kk >> 3) & 1) * 32) + (r & 31);
    ushort4 h;
    h.x = bf16rne(v.x); h.y = bf16rne(v.y); h.z = bf16rne(v.z); h.w = bf16rne(v.w);
    *(ushort4*)((char*)dst + (size_t)idx * 16 + ((kk & 4) * 2)) = h;
}

__global__ void k_init(int* pos_of, float* accp) {
    int i = blockIdx.x * 256 + threadIdx.x;
    if (i < N_CAND) pos_of[i] = -1;
    if (i == 0) accp[0] = 0.f;
}

__global__ void k_scatter(const int* __restrict__ trg, int* __restrict__ pos_of) {
    int j = threadIdx.x;   // 256 threads; atomicMax => last batch row wins on duplicates
    atomicMax(&pos_of[trg[j]], j);
}

__global__ __launch_bounds__(256) void k_prep(const float* __restrict__ features,
                                              const float* __restrict__ W,
                                              const float* __restrict__ bias,
                                              float* __restrict__ f_norm,
                                              float* __restrict__ softm) {
    int b = blockIdx.x, t = threadIdx.x;
    __shared__ float row[256];
    __shared__ float red[256];
    float x = features[b * D_DIM + t];
    row[t] = x; red[t] = x * x;
    __syncthreads();
    for (int s = 128; s > 0; s >>= 1) {
        if (t < s) red[t] += red[t + s];
        __syncthreads();
    }
    float nrm = fmaxf(sqrtf(red[0]), 1e-12f);
    f_norm[b * D_DIM + t] = x / nrm;
    if (t < C_DIM) {
        float acc = bias[t];
        for (int d = 0; d < D_DIM; ++d) acc = fmaf(row[d], W[d * C_DIM + t], acc);
        float mx = acc;
        for (int off = 32; off > 0; off >>= 1) mx = fmaxf(mx, __shfl_xor(mx, off, 64));
        float e = expf(acc - mx);
        float ssum = e;
        for (int off = 32; off > 0; off >>= 1) ssum += __shfl_xor(ssum, off, 64);
        softm[b * C_DIM + t] = e / ssum;
    }
}

// MFMA distance + fused per-(query,slab) top-6.
// Block: 256 thr = 4 waves; 64-query tile, slab of 1024 candidates in 16 chunks of 64.
// Wave w: candgrp cg=w&1 (32 of 64 chunk cands), qgrp qg=w>>1 (32 of 64 queries).
// mfma_f32_32x32x16_bf16: A[m][k] lane: m=l&31, k=(l>>5)*8+j. B[k][n] lane: n=l&31,
// k=(l>>5)*8+j. C: col(n)=l&31, row(m)=(reg&3)+8*(reg>>2)+4*(l>>5).
__global__ __launch_bounds__(256) void dist_topk(const float* __restrict__ Qm,
                                                 const float* __restrict__ fea_bank,
                                                 const float* __restrict__ f_norm,
                                                 const int* __restrict__ pos_of,
                                                 float* __restrict__ pval,
                                                 int* __restrict__ pidx,
                                                 int nqt, int swz) {
    __shared__ __align__(16) short cs_l[CHUNK * D_DIM];   // 32 KB
    __shared__ __align__(16) short qs_l[64 * D_DIM];      // 32 KB (reused for merge)

    int slab, qt;
    if (swz) {
        int bid = blockIdx.x;
        int xcd = bid & 7;
        int rem = bid >> 3;
        qt = rem % nqt;
        slab = (rem / nqt) * 8 + xcd;
        if (slab >= NSLABS) return;
    } else {
        slab = blockIdx.x;
        qt = blockIdx.y;
    }

    const int t   = threadIdx.x;
    const int w   = t >> 6;
    const int l   = t & 63;
    const int cg  = w & 1;
    const int qg  = w >> 1;
    const int col = l & 31;
    const int khv = l >> 5;

    // ---- stage query tile (fp32 -> bf16 RNE) ----
    {
        int r = t >> 2, q4 = t & 3;
        const float* src = Qm + (size_t)(qt * 64 + r) * D_DIM;
        #pragma unroll
        for (int i = 0; i < 16; ++i) {
            int kk = q4 * 64 + i * 4;
            float4 v = *(const float4*)(src + kk);
            stage16(qs_l, r, kk, v);
        }
    }
    __syncthreads();

    // ---- preload all 16 B-fragments (queries) into registers ----
    bf16x8 bfr[16];
    #pragma unroll
    for (int ks = 0; ks < 16; ++ks)
        bfr[ks] = *(const bf16x8*)(qs_l + (size_t)(ks * 128 + qg * 64 + khv * 32 + col) * 8);

    float lv[6]; int li[6];
    #pragma unroll
    for (int k = 0; k < 6; ++k) { lv[k] = -3.4e38f; li[k] = 0x7fffffff; }

    for (int ch = 0; ch < NCHUNK; ++ch) {
        const int cbase = slab * SLAB + ch * CHUNK;
        __syncthreads();   // previous chunk's compute done before cs_l overwrite
        {
            int r = t >> 2, q4 = t & 3;
            int n = cbase + r;
            int nc = n < N_CAND ? n : N_CAND - 1;
            int p = pos_of[nc];
            const float* src = (p >= 0) ? (f_norm + (size_t)p * D_DIM)
                                        : (fea_bank + (size_t)nc * D_DIM);
            #pragma unroll
            for (int i = 0; i < 16; ++i) {
                int kk = q4 * 64 + i * 4;
                float4 v = *(const float4*)(src + kk);
                stage16(cs_l, r, kk, v);
            }
        }
        __syncthreads();

        f32x16 acc0 = {};
        f32x16 acc1 = {};
        #pragma unroll
        for (int ks = 0; ks < 16; ks += 2) {
            bf16x8 a0 = *(const bf16x8*)(cs_l + (size_t)((ks    ) * 128 + cg * 64 + khv * 32 + col) * 8);
            bf16x8 a1 = *(const bf16x8*)(cs_l + (size_t)((ks + 1) * 128 + cg * 64 + khv * 32 + col) * 8);
            acc0 = __builtin_amdgcn_mfma_f32_32x32x16_bf16(a0, bfr[ks    ], acc0, 0, 0, 0);
            acc1 = __builtin_amdgcn_mfma_f32_32x32x16_bf16(a1, bfr[ks + 1], acc1, 0, 0, 0);
        }

        #pragma unroll
        for (int reg = 0; reg < 16; ++reg) {
            float v = acc0[reg] + acc1[reg];
            int m = (reg & 3) + 8 * (reg >> 2) + 4 * khv;
            int n = cbase + cg * 32 + m;
            if (n < N_CAND) insert6(lv, li, v, n);
        }
    }

    // ---- per-slab merge: 4 source lists per query (qs_l reused) ----
    __syncthreads();
    float* mlv = (float*)qs_l;                       // [64][4][6] floats (6144 B)
    int*   mli = (int*)((char*)qs_l + 8192);         // [64][4][6] ints
    int ql = qg * 32 + col;
    int sid = cg * 2 + khv;
    #pragma unroll
    for (int k = 0; k < 6; ++k) {
        mlv[(ql * 4 + sid) * 6 + k] = lv[k];
        mli[(ql * 4 + sid) * 6 + k] = li[k];
    }
    __syncthreads();
    if (t < 64) {
        float fv[6]; int fi[6];
        #pragma unroll
        for (int k = 0; k < 6; ++k) { fv[k] = -3.4e38f; fi[k] = 0x7fffffff; }
        for (int s = 0; s < 4; ++s)
            #pragma unroll
            for (int k = 0; k < 6; ++k)
                insert6(fv, fi, mlv[(t * 4 + s) * 6 + k], mli[(t * 4 + s) * 6 + k]);
        size_t base = ((size_t)(qt * 64 + t) * NSLABS + slab) * 6;
        #pragma unroll
        for (int k = 0; k < 6; ++k) { pval[base + k] = fv[k]; pidx[base + k] = fi[k]; }
    }
}

__global__ __launch_bounds__(256) void topk_merge(const float* __restrict__ pval,
                                                  const int* __restrict__ pidx,
                                                  int* __restrict__ out_idx) {
    int q = blockIdx.x, t = threadIdx.x;
    const int total = NSLABS * 6;
    float lv[6]; int li[6];
    #pragma unroll
    for (int k = 0; k < 6; ++k) { lv[k] = -3.4e38f; li[k] = 0x7fffffff; }
    size_t base = (size_t)q * total;
    for (int e = t; e < total; e += 256) insert6(lv, li, pval[base + e], pidx[base + e]);
    __shared__ float sv[256][6];
    __shared__ int   si[256][6];
    #pragma unroll
    for (int k = 0; k < 6; ++k) { sv[t][k] = lv[k]; si[t][k] = li[k]; }
    __syncthreads();
    for (int w = 128; w >= 1; w >>= 1) {
        if (t < w) {
            float ov[6]; int oi[6];
            merge6(sv[t], si[t], sv[t + w], si[t + w], ov, oi);
            #pragma unroll
            for (int k = 0; k < 6; ++k) { sv[t][k] = ov[k]; si[t][k] = oi[k]; }
        }
        __syncthreads();
    }
    if (t == 0) {
        for (int k = 1; k < 6; ++k) out_idx[q * K_TOP + k - 1] = si[0][k];
    }
}

__global__ void k_gather(const int* __restrict__ idx, const float* __restrict__ fea_bank,
                         const float* __restrict__ f_norm, const int* __restrict__ pos_of,
                         float* __restrict__ Q2) {
    int r = blockIdx.x, t = threadIdx.x;   // 64 threads
    int n = idx[r];
    int p = pos_of[n];
    const float* src = (p >= 0) ? (f_norm + (size_t)p * D_DIM)
                                : (fea_bank + (size_t)n * D_DIM);
    float4 v = ((const float4*)src)[t];
    ((float4*)(Q2 + (size_t)r * D_DIM))[t] = v;
}

__global__ void k_loss(const float* __restrict__ softm, const float* __restrict__ score_bank,
                       const int* __restrict__ pos_of, const int* __restrict__ idx_near,
                       const int* __restrict__ idx_nn, const int* __restrict__ trg,
                       float* accp) {
    int b = blockIdx.x, c = threadIdx.x;   // 64 threads
    float p_bc = softm[b * C_DIM + c];
    float part = 0.f;
    for (int k = 0; k < K_TOP; ++k) {
        for (int j = 0; j < K_TOP; ++j) {
            int n = idx_nn[(b * K_TOP + k) * K_TOP + j];
            int p = pos_of[n];
            const float* srow = (p >= 0) ? (softm + (size_t)p * C_DIM)
                                         : (score_bank + (size_t)n * C_DIM);
            float s = srow[c];
            float v = s * (logf(s) - p_bc);
            for (int off = 32; off > 0; off >>= 1) v += __shfl_down(v, off, 64);
            if (c == 0) part += 0.1f * v;
        }
    }
    for (int k = 0; k < K_TOP; ++k) {
        int n = idx_near[b * K_TOP + k];
        int p = pos_of[n];
        const float* srow = (p >= 0) ? (softm + (size_t)p * C_DIM)
                                     : (score_bank + (size_t)n * C_DIM);
        float s = srow[c];
        float v = s * (logf(s) - p_bc);
        for (int off = 32; off > 0; off >>= 1) v += __shfl_down(v, off, 64);
        if (c == 0) {
            int m = 0;
            for (int j = 0; j < K_TOP; ++j)
                m += (idx_nn[(b * K_TOP + k) * K_TOP + j] == trg[b]) ? 1 : 0;
            float w = (m > 0) ? (float)m : 0.1f;
            part += w * v;
        }
    }
    if (c == 0) atomicAdd(accp, part * (1.0f / (float)B_SZ));
}

__global__ void k_final(const float* __restrict__ softm, const float* __restrict__ accp,
                        float* __restrict__ out) {
    int c = threadIdx.x;   // 64
    float m = 0.f;
    for (int b = 0; b < B_SZ; ++b) m += softm[b * C_DIM + c];
    m *= (1.0f / (float)B_SZ);
    float g = m * logf(m + 1e-5f);
    for (int off = 32; off > 0; off >>= 1) g += __shfl_down(g, off, 64);
    if (c == 0) out[0] = accp[0] + g;
}

extern "C" void kernel_launch(void* const* d_in, const int* in_sizes, int n_in,
                              void* d_out, int out_size, void* d_ws, size_t ws_size,
                              hipStream_t stream) {
    const float* features   = (const float*)d_in[0];
    const float* W          = (const float*)d_in[1];
    const float* bias       = (const float*)d_in[2];
    const float* fea_bank   = (const float*)d_in[3];
    const float* score_bank = (const float*)d_in[4];
    const int*   trg        = (const int*)d_in[5];
    float* out = (float*)d_out;

    char* ws = (char*)d_ws;
    size_t off = 0;
    auto alloc = [&](size_t bytes) -> void* {
        void* p = ws + off;
        off = (off + bytes + 255) & ~(size_t)255;
        return p;
    };
    float* f_norm   = (float*)alloc((size_t)B_SZ * D_DIM * 4);
    float* softm    = (float*)alloc((size_t)B_SZ * C_DIM * 4);
    int*   pos_of   = (int*)alloc((size_t)N_CAND * 4);
    float* accp     = (float*)alloc(4);
    int*   idx_near = (int*)alloc((size_t)B_SZ * K_TOP * 4);
    int*   idx_nn   = (int*)alloc((size_t)B_SZ * K_TOP * K_TOP * 4);
    float* Q2       = (float*)alloc((size_t)B_SZ * K_TOP * D_DIM * 4);
    float* pv1      = (float*)alloc((size_t)B_SZ * NSLABS * 6 * 4);
    int*   pi1      = (int*)alloc((size_t)B_SZ * NSLABS * 6 * 4);
    float* pv2      = (float*)alloc((size_t)B_SZ * K_TOP * NSLABS * 6 * 4);
    int*   pi2      = (int*)alloc((size_t)B_SZ * K_TOP * NSLABS * 6 * 4);

    k_init<<<dim3((N_CAND + 255) / 256), dim3(256), 0, stream>>>(pos_of, accp);
    k_scatter<<<dim3(1), dim3(256), 0, stream>>>(trg, pos_of);
    k_prep<<<dim3(B_SZ), dim3(256), 0, stream>>>(features, W, bias, f_norm, softm);

    // pass 1: 256 queries (4 qtiles), plain grid
    dist_topk<<<dim3(NSLABS, B_SZ / 64), dim3(256), 0, stream>>>(
        f_norm, fea_bank, f_norm, pos_of, pv1, pi1, B_SZ / 64, 0);
    topk_merge<<<dim3(B_SZ), dim3(256), 0, stream>>>(pv1, pi1, idx_near);

    k_gather<<<dim3(B_SZ * K_TOP), dim3(64), 0, stream>>>(idx_near, fea_bank, f_norm, pos_of, Q2);

    // pass 2: 1280 queries (20 qtiles), XCD-grouped bid mapping (same slab -> same XCD)
    {
        int nqt = (B_SZ * K_TOP) / 64;            // 20
        int nsg = (NSLABS + 7) / 8;               // 25
        dist_topk<<<dim3(nsg * 8 * nqt), dim3(256), 0, stream>>>(
            Q2, fea_bank, f_norm, pos_of, pv2, pi2, nqt, 1);
    }
    topk_merge<<<dim3(B_SZ * K_TOP), dim3(256), 0, stream>>>(pv2, pi2, idx_nn);

    k_loss<<<dim3(B_SZ), dim3(64), 0, stream>>>(softm, score_bank, pos_of, idx_near, idx_nn, trg, accp);
    k_final<<<dim3(1), dim3(64), 0, stream>>>(softm, accp, out);
}